// Round 15
// baseline (75.612 us; speedup 1.0000x reference)
//
#include <hip/hip_runtime.h>
#include <hip/hip_bf16.h>
#include <hip/hip_fp8.h>

#define N_NODES 10000
#define N_EDGES 160000
#define D_IN 512
#define D_OUT 512
#define K_TOT 1024   // concat [x | neigh]
#define SLOTS 128    // fixed-stride CSR slots per node

typedef __attribute__((ext_vector_type(8))) short short8;
typedef __attribute__((ext_vector_type(4))) float f32x4;
typedef __attribute__((ext_vector_type(2))) float f32x2;

__device__ __forceinline__ void load_lds16(const void* g, void* l) {
    __builtin_amdgcn_global_load_lds(
        (const __attribute__((address_space(1))) void*)g,
        (__attribute__((address_space(3))) void*)l, 16, 0, 0);
}

__device__ __forceinline__ float bf16_to_f32(unsigned short u) {
    union { unsigned int i; float f; } c;
    c.i = ((unsigned int)u) << 16;
    return c.f;
}

#if defined(__has_builtin) && __has_builtin(__builtin_amdgcn_cvt_pk_fp8_f32) && \
    __has_builtin(__builtin_amdgcn_cvt_pk_f32_fp8)
#define HW_FP8 1
#else
#define HW_FP8 0
#endif

__device__ __forceinline__ unsigned int enc_fp8x4(float a, float b, float c, float d) {
#if HW_FP8
    int v = __builtin_amdgcn_cvt_pk_fp8_f32(a, b, 0, false);
    v = __builtin_amdgcn_cvt_pk_fp8_f32(c, d, v, true);
    return (unsigned int)v;
#else
    __hip_fp8_e4m3 q0(a), q1(b), q2(c), q3(d);
    return (unsigned int)q0.__x | ((unsigned int)q1.__x << 8) |
           ((unsigned int)q2.__x << 16) | ((unsigned int)q3.__x << 24);
#endif
}

__device__ __forceinline__ void dec_fp8x4_add(float* acc, unsigned int v) {
#if HW_FP8
    f32x2 lo = __builtin_amdgcn_cvt_pk_f32_fp8((int)v, false);
    f32x2 hi = __builtin_amdgcn_cvt_pk_f32_fp8((int)v, true);
    acc[0] += lo.x; acc[1] += lo.y; acc[2] += hi.x; acc[3] += hi.y;
#else
#pragma unroll
    for (int i = 0; i < 4; ++i) {
        __hip_fp8_e4m3 q; q.__x = (unsigned char)(v >> (8 * i));
        acc[i] += (float)q;
    }
#endif
}

// ---------------- K1: scatter-count (0..624) | W-transpose (625..1136) | convert_x (1137..3636) --

__global__ __launch_bounds__(256) void k1_prep(const int* __restrict__ src,
                                               const int* __restrict__ dst,
                                               int* __restrict__ deg,
                                               int* __restrict__ csr_src,
                                               const float* __restrict__ Wself,
                                               const float* __restrict__ Wneigh,
                                               __hip_bfloat16* __restrict__ Wt,
                                               const float* __restrict__ x,
                                               __hip_bfloat16* __restrict__ A,
                                               unsigned int* __restrict__ x8) {
    int bid = blockIdx.x;
    int tid = threadIdx.x;
    if (bid < 625) {
        int e = bid * 256 + tid;                       // exactly 160000
        int d = dst[e];
        int slot = atomicAdd(&deg[d], 1);
        if (slot < SLOTS) csr_src[d * SLOTS + slot] = src[e];
        return;
    }
    if (bid < 1137) {
        __shared__ float tl[32][33];
        int b = bid - 625;
        int kt0 = (b & 31) * 32;
        int nt0 = (b >> 5) * 32;
        int tx = tid & 31, ty = tid >> 5;
        const float* Wsrc = (kt0 < D_IN) ? (Wself + (size_t)kt0 * D_OUT)
                                         : (Wneigh + (size_t)(kt0 - D_IN) * D_OUT);
#pragma unroll
        for (int p = 0; p < 4; ++p)
            tl[p * 8 + ty][tx] = Wsrc[(size_t)(p * 8 + ty) * D_OUT + nt0 + tx];
        __syncthreads();
#pragma unroll
        for (int p = 0; p < 4; ++p)
            Wt[(size_t)(nt0 + p * 8 + ty) * K_TOT + kt0 + tx] =
                __float2bfloat16(tl[tx][p * 8 + ty]);
        return;
    }
    // convert_x: bf16 into A[:, 0:512], fp8 into x8
    int gid = (bid - 1137) * 256 + tid;                // exactly 640000
    int row = gid >> 6;
    int col = (gid & 63) * 8;
    const float4* p = (const float4*)(x + (size_t)row * D_IN + col);
    float4 u = p[0], v = p[1];
    union { short8 s; __hip_bfloat16 h[8]; } o;
    o.h[0] = __float2bfloat16(u.x); o.h[1] = __float2bfloat16(u.y);
    o.h[2] = __float2bfloat16(u.z); o.h[3] = __float2bfloat16(u.w);
    o.h[4] = __float2bfloat16(v.x); o.h[5] = __float2bfloat16(v.y);
    o.h[6] = __float2bfloat16(v.z); o.h[7] = __float2bfloat16(v.w);
    *(short8*)(A + (size_t)row * K_TOT + col) = o.s;
    uint2 q;
    q.x = enc_fp8x4(u.x, u.y, u.z, u.w);
    q.y = enc_fp8x4(v.x, v.y, v.z, v.w);
    *(uint2*)(x8 + ((size_t)row * D_IN + col) / 4) = q;
}

// ---------------- K2: aggregation — one wave per node, fp8 gather (512B rows) ----------------

__global__ __launch_bounds__(256) void aggregate_kernel(const int* __restrict__ deg,
                                                        const int* __restrict__ csr_src,
                                                        const unsigned int* __restrict__ x8,
                                                        __hip_bfloat16* __restrict__ A) {
    int wave = threadIdx.x >> 6, lane = threadIdx.x & 63;
    int node = blockIdx.x * 4 + wave;
    if (node >= N_NODES) return;
    int cnt = deg[node];
    if (cnt > SLOTS) cnt = SLOTS;
    const int* ebase = csr_src + (size_t)node * SLOTS;
    const int w0 = lane * 2;
    float acc[8];
#pragma unroll
    for (int i = 0; i < 8; ++i) acc[i] = 0.f;
    for (int base = 0; base < cnt; base += 64) {
        int m = cnt - base; if (m > 64) m = 64;
        int idx = (base + lane < cnt) ? ebase[base + lane] : 0;
        int j = 0;
        for (; j + 3 < m; j += 4) {
            int s0 = __shfl(idx, j), s1 = __shfl(idx, j + 1);
            int s2 = __shfl(idx, j + 2), s3 = __shfl(idx, j + 3);
            uint2 v0 = *(const uint2*)(x8 + (size_t)s0 * (D_IN / 4) + w0);
            uint2 v1 = *(const uint2*)(x8 + (size_t)s1 * (D_IN / 4) + w0);
            uint2 v2 = *(const uint2*)(x8 + (size_t)s2 * (D_IN / 4) + w0);
            uint2 v3 = *(const uint2*)(x8 + (size_t)s3 * (D_IN / 4) + w0);
            dec_fp8x4_add(acc, v0.x); dec_fp8x4_add(acc + 4, v0.y);
            dec_fp8x4_add(acc, v1.x); dec_fp8x4_add(acc + 4, v1.y);
            dec_fp8x4_add(acc, v2.x); dec_fp8x4_add(acc + 4, v2.y);
            dec_fp8x4_add(acc, v3.x); dec_fp8x4_add(acc + 4, v3.y);
        }
        for (; j < m; ++j) {
            int s0 = __shfl(idx, j);
            uint2 v0 = *(const uint2*)(x8 + (size_t)s0 * (D_IN / 4) + w0);
            dec_fp8x4_add(acc, v0.x); dec_fp8x4_add(acc + 4, v0.y);
        }
    }
    float inv = 1.0f / fmaxf((float)cnt, 1.0f);
    union { short8 s; __hip_bfloat16 h[8]; } o;
#pragma unroll
    for (int i = 0; i < 8; ++i) o.h[i] = __float2bfloat16(acc[i] * inv);
    *(short8*)(A + (size_t)node * K_TOT + D_IN + lane * 8) = o.s;
}

// ---------------- K3: GEMM 128x128, BK=32, 4 waves x (64x64), ext-XOR swizzle,
//                  dbuf prefetch, bijective XCD swizzle (316 = 8*39+4) ----------------

__global__ __launch_bounds__(256, 3) void gemm_kernel(const short* __restrict__ A,
                                                      const short* __restrict__ Wt,
                                                      const float* __restrict__ bias,
                                                      float* __restrict__ H) {
    __shared__ __align__(16) short smA[2][128 * 32];   // 2 x 8 KB
    __shared__ __align__(16) short smB[2][128 * 32];   // 2 x 8 KB
    const int tid = threadIdx.x;
    const int wave = tid >> 6, lane = tid & 63;

    // bijective XCD swizzle for nwg=316: q=39, r=4
    const int xcd = blockIdx.x & 7;
    const int k = blockIdx.x >> 3;
    const int wgid = ((xcd < 4) ? xcd * 40 : 160 + (xcd - 4) * 39) + k;
    const int m0 = (wgid >> 2) * 128;                  // 79 m-panels
    const int n0 = (wgid & 3) * 128;                   // 4 n-panels

    const int wm = wave >> 1, wn = wave & 1;
    const int rr = lane & 15, kq = lane >> 4;
    const int grr = (rr & 3) ^ ((rr >> 2) & 3);        // read-side XOR term

    // staging: lane l covers row (l>>2) of a 16-row group, global chunk pre-swizzled
    const int lrow = lane >> 2;
    const int schunk = (lane & 3) ^ ((lane >> 2) & 3) ^ ((lane >> 4) & 3);

    f32x4 acc[4][4];
#pragma unroll
    for (int i = 0; i < 4; ++i)
#pragma unroll
        for (int j = 0; j < 4; ++j) acc[i][j] = (f32x4){0.f, 0.f, 0.f, 0.f};

    // A rows: wave*32 + {0,16} + lrow (clamped); B rows: n0 + same
    int garow[2];
#pragma unroll
    for (int i = 0; i < 2; ++i) {
        int gr = m0 + wave * 32 + i * 16 + lrow;
        garow[i] = (gr > N_NODES - 1) ? N_NODES - 1 : gr;
    }
    int gbrow[2];
#pragma unroll
    for (int i = 0; i < 2; ++i) gbrow[i] = n0 + wave * 32 + i * 16 + lrow;  // < 512

    auto stage = [&](int buf, int kt) {
        const int kb = kt * 32 + schunk * 8;           // bf16 offset within row
#pragma unroll
        for (int i = 0; i < 2; ++i)
            load_lds16(A + (size_t)garow[i] * K_TOT + kb,
                       (char*)smA[buf] + (wave * 32 + i * 16) * 64);
#pragma unroll
        for (int i = 0; i < 2; ++i)
            load_lds16(Wt + (size_t)gbrow[i] * K_TOT + kb,
                       (char*)smB[buf] + (wave * 32 + i * 16) * 64);
    };

    stage(0, 0);
    __syncthreads();

    for (int kt = 0; kt < K_TOT / 32; ++kt) {
        const int cur = kt & 1;
        if (kt + 1 < K_TOT / 32) stage(cur ^ 1, kt + 1);

        short8 afr[4], bfr[4];
#pragma unroll
        for (int mf = 0; mf < 4; ++mf) {
            int row = wm * 64 + mf * 16 + rr;
            int pch = kq ^ grr;
            afr[mf] = *(const short8*)&smA[cur][row * 32 + pch * 8];
        }
#pragma unroll
        for (int nf = 0; nf < 4; ++nf) {
            int row = wn * 64 + nf * 16 + rr;
            int pch = kq ^ grr;
            bfr[nf] = *(const short8*)&smB[cur][row * 32 + pch * 8];
        }
#pragma unroll
        for (int mf = 0; mf < 4; ++mf)
#pragma unroll
            for (int nf = 0; nf < 4; ++nf)
                acc[mf][nf] = __builtin_amdgcn_mfma_f32_16x16x32_bf16(
                    afr[mf], bfr[nf], acc[mf][nf], 0, 0, 0);
        __syncthreads();
    }

    // epilogue: bias + leaky_relu.  C/D: col=lane&15, row=(lane>>4)*4+reg
#pragma unroll
    for (int mf = 0; mf < 4; ++mf) {
        int row = m0 + wm * 64 + mf * 16 + kq * 4;
#pragma unroll
        for (int nf = 0; nf < 4; ++nf) {
            int col = n0 + wn * 64 + nf * 16 + rr;
            float bv = bias[col];
#pragma unroll
            for (int r = 0; r < 4; ++r) {
                int grow = row + r;
                if (grow < N_NODES) {
                    float v = acc[mf][nf][r] + bv;
                    v = (v >= 0.f) ? v : 0.01f * v;
                    H[(size_t)grow * D_OUT + col] = v;
                }
            }
        }
    }
}

// ---------------- K4: row-wise L2 normalize (in place) ----------------

__global__ __launch_bounds__(256) void normalize_kernel(float* __restrict__ H) {
    int wave = threadIdx.x >> 6, lane = threadIdx.x & 63;
    int row = blockIdx.x * 4 + wave;
    if (row >= N_NODES) return;
    float4* p = (float4*)(H + (size_t)row * D_OUT + lane * 8);
    float4 u = p[0], v = p[1];
    float s = u.x * u.x + u.y * u.y + u.z * u.z + u.w * u.w +
              v.x * v.x + v.y * v.y + v.z * v.z + v.w * v.w;
#pragma unroll
    for (int o = 32; o > 0; o >>= 1) s += __shfl_xor(s, o);
    float scale = 1.0f / fmaxf(sqrtf(s), 1e-12f);
    u.x *= scale; u.y *= scale; u.z *= scale; u.w *= scale;
    v.x *= scale; v.y *= scale; v.z *= scale; v.w *= scale;
    p[0] = u; p[1] = v;
}

// ---------------- launch ----------------

extern "C" void kernel_launch(void* const* d_in, const int* in_sizes, int n_in,
                              void* d_out, int out_size, void* d_ws, size_t ws_size,
                              hipStream_t stream) {
    const float* x      = (const float*)d_in[0];
    const int*   src    = (const int*)d_in[1];
    const int*   dst    = (const int*)d_in[2];
    const float* Wself  = (const float*)d_in[3];
    const float* Wneigh = (const float*)d_in[4];
    const float* bias   = (const float*)d_in[5];
    float* H = (float*)d_out;

    char* ws = (char*)d_ws;
    int* deg     = (int*)ws;                          // 10000
    int* csr_src = deg + N_NODES;                     // 10000*128 ints
    size_t int_bytes = ((size_t)(N_NODES + N_NODES * SLOTS) * 4 + 255) & ~(size_t)255;
    __hip_bfloat16* Abuf = (__hip_bfloat16*)(ws + int_bytes);        // [10000][1024]
    __hip_bfloat16* Wt   = Abuf + (size_t)N_NODES * K_TOT;           // [512][1024]
    unsigned int*   x8   = (unsigned int*)(Wt + (size_t)D_OUT * K_TOT); // [10000][512] fp8

    hipMemsetAsync(deg, 0, N_NODES * sizeof(int), stream);

    k1_prep<<<625 + 512 + 2500, 256, 0, stream>>>(src, dst, deg, csr_src,
                                                  Wself, Wneigh, Wt, x, Abuf, x8);
    aggregate_kernel<<<2500, 256, 0, stream>>>(deg, csr_src, x8, Abuf);
    gemm_kernel<<<316, 256, 0, stream>>>((const short*)Abuf, (const short*)Wt, bias, H);
    normalize_kernel<<<2500, 256, 0, stream>>>(H);
}

// Round 16
// 68.363 us; speedup vs baseline: 1.1060x; 1.1060x over previous
//
#include <hip/hip_runtime.h>
#include <hip/hip_bf16.h>
#include <hip/hip_fp8.h>

#define N_NODES 10000
#define N_EDGES 160000
#define D_IN 512
#define D_OUT 512
#define K_TOT 1024   // concat [x | neigh]
#define BK 64
#define SLOTS 128    // fixed-stride CSR slots per node

typedef __attribute__((ext_vector_type(8))) short short8;
typedef __attribute__((ext_vector_type(4))) float f32x4;
typedef __attribute__((ext_vector_type(2))) float f32x2;

__device__ __forceinline__ void load_lds16(const void* g, void* l) {
    __builtin_amdgcn_global_load_lds(
        (const __attribute__((address_space(1))) void*)g,
        (__attribute__((address_space(3))) void*)l, 16, 0, 0);
}

__device__ __forceinline__ float bf16_to_f32(unsigned short u) {
    union { unsigned int i; float f; } c;
    c.i = ((unsigned int)u) << 16;
    return c.f;
}

#if defined(__has_builtin) && __has_builtin(__builtin_amdgcn_cvt_pk_fp8_f32) && \
    __has_builtin(__builtin_amdgcn_cvt_pk_f32_fp8)
#define HW_FP8 1
#else
#define HW_FP8 0
#endif

__device__ __forceinline__ unsigned int enc_fp8x4(float a, float b, float c, float d) {
#if HW_FP8
    int v = __builtin_amdgcn_cvt_pk_fp8_f32(a, b, 0, false);   // bytes 0,1
    v = __builtin_amdgcn_cvt_pk_fp8_f32(c, d, v, true);        // bytes 2,3
    return (unsigned int)v;
#else
    __hip_fp8_e4m3 q0(a), q1(b), q2(c), q3(d);
    return (unsigned int)q0.__x | ((unsigned int)q1.__x << 8) |
           ((unsigned int)q2.__x << 16) | ((unsigned int)q3.__x << 24);
#endif
}

__device__ __forceinline__ void dec_fp8x4_add(float* acc, unsigned int v) {
#if HW_FP8
    f32x2 lo = __builtin_amdgcn_cvt_pk_f32_fp8((int)v, false); // bytes 0,1
    f32x2 hi = __builtin_amdgcn_cvt_pk_f32_fp8((int)v, true);  // bytes 2,3
    acc[0] += lo.x; acc[1] += lo.y; acc[2] += hi.x; acc[3] += hi.y;
#else
#pragma unroll
    for (int i = 0; i < 4; ++i) {
        __hip_fp8_e4m3 q; q.__x = (unsigned char)(v >> (8 * i));
        acc[i] += (float)q;
    }
#endif
}

// ---------------- K1: scatter-count (0..624) | W-transpose (625..1136) | convert_x (1137..3636) --

__global__ __launch_bounds__(256) void k1_prep(const int* __restrict__ src,
                                               const int* __restrict__ dst,
                                               int* __restrict__ deg,
                                               int* __restrict__ csr_src,
                                               const float* __restrict__ Wself,
                                               const float* __restrict__ Wneigh,
                                               __hip_bfloat16* __restrict__ Wt,
                                               const float* __restrict__ x,
                                               __hip_bfloat16* __restrict__ A,
                                               unsigned int* __restrict__ x8) {
    int bid = blockIdx.x;
    int tid = threadIdx.x;
    if (bid < 625) {
        int e = bid * 256 + tid;                       // exactly 160000
        int d = dst[e];
        int slot = atomicAdd(&deg[d], 1);
        if (slot < SLOTS) csr_src[d * SLOTS + slot] = src[e];
        return;
    }
    if (bid < 1137) {
        __shared__ float tl[32][33];
        int b = bid - 625;
        int kt0 = (b & 31) * 32;
        int nt0 = (b >> 5) * 32;
        int tx = tid & 31, ty = tid >> 5;
        const float* Wsrc = (kt0 < D_IN) ? (Wself + (size_t)kt0 * D_OUT)
                                         : (Wneigh + (size_t)(kt0 - D_IN) * D_OUT);
#pragma unroll
        for (int p = 0; p < 4; ++p)
            tl[p * 8 + ty][tx] = Wsrc[(size_t)(p * 8 + ty) * D_OUT + nt0 + tx];
        __syncthreads();
#pragma unroll
        for (int p = 0; p < 4; ++p)
            Wt[(size_t)(nt0 + p * 8 + ty) * K_TOT + kt0 + tx] =
                __float2bfloat16(tl[tx][p * 8 + ty]);
        return;
    }
    // convert_x: bf16 into A[:, 0:512], fp8 into x8
    int gid = (bid - 1137) * 256 + tid;                // exactly 640000
    int row = gid >> 6;
    int col = (gid & 63) * 8;
    const float4* p = (const float4*)(x + (size_t)row * D_IN + col);
    float4 u = p[0], v = p[1];
    union { short8 s; __hip_bfloat16 h[8]; } o;
    o.h[0] = __float2bfloat16(u.x); o.h[1] = __float2bfloat16(u.y);
    o.h[2] = __float2bfloat16(u.z); o.h[3] = __float2bfloat16(u.w);
    o.h[4] = __float2bfloat16(v.x); o.h[5] = __float2bfloat16(v.y);
    o.h[6] = __float2bfloat16(v.z); o.h[7] = __float2bfloat16(v.w);
    *(short8*)(A + (size_t)row * K_TOT + col) = o.s;
    uint2 q;
    q.x = enc_fp8x4(u.x, u.y, u.z, u.w);
    q.y = enc_fp8x4(v.x, v.y, v.z, v.w);
    *(uint2*)(x8 + ((size_t)row * D_IN + col) / 4) = q;
}

// ---------------- K2: aggregation — one wave per node, fp8 gather (512B rows) ----------------

__global__ __launch_bounds__(256) void aggregate_kernel(const int* __restrict__ deg,
                                                        const int* __restrict__ csr_src,
                                                        const unsigned int* __restrict__ x8,
                                                        __hip_bfloat16* __restrict__ A) {
    int wave = threadIdx.x >> 6, lane = threadIdx.x & 63;
    int node = blockIdx.x * 4 + wave;
    if (node >= N_NODES) return;
    int cnt = deg[node];
    if (cnt > SLOTS) cnt = SLOTS;
    const int* ebase = csr_src + (size_t)node * SLOTS;
    const int w0 = lane * 2;                  // 2 u32 = 8 fp8 per lane; 64 lanes = 512B row
    float acc[8];
#pragma unroll
    for (int i = 0; i < 8; ++i) acc[i] = 0.f;
    for (int base = 0; base < cnt; base += 64) {
        int m = cnt - base; if (m > 64) m = 64;
        int idx = (base + lane < cnt) ? ebase[base + lane] : 0;
        int j = 0;
        for (; j + 3 < m; j += 4) {
            int s0 = __shfl(idx, j), s1 = __shfl(idx, j + 1);
            int s2 = __shfl(idx, j + 2), s3 = __shfl(idx, j + 3);
            uint2 v0 = *(const uint2*)(x8 + (size_t)s0 * (D_IN / 4) + w0);
            uint2 v1 = *(const uint2*)(x8 + (size_t)s1 * (D_IN / 4) + w0);
            uint2 v2 = *(const uint2*)(x8 + (size_t)s2 * (D_IN / 4) + w0);
            uint2 v3 = *(const uint2*)(x8 + (size_t)s3 * (D_IN / 4) + w0);
            dec_fp8x4_add(acc, v0.x); dec_fp8x4_add(acc + 4, v0.y);
            dec_fp8x4_add(acc, v1.x); dec_fp8x4_add(acc + 4, v1.y);
            dec_fp8x4_add(acc, v2.x); dec_fp8x4_add(acc + 4, v2.y);
            dec_fp8x4_add(acc, v3.x); dec_fp8x4_add(acc + 4, v3.y);
        }
        for (; j < m; ++j) {
            int s0 = __shfl(idx, j);
            uint2 v0 = *(const uint2*)(x8 + (size_t)s0 * (D_IN / 4) + w0);
            dec_fp8x4_add(acc, v0.x); dec_fp8x4_add(acc + 4, v0.y);
        }
    }
    float inv = 1.0f / fmaxf((float)cnt, 1.0f);
    union { short8 s; __hip_bfloat16 h[8]; } o;
#pragma unroll
    for (int i = 0; i < 8; ++i) o.h[i] = __float2bfloat16(acc[i] * inv);
    *(short8*)(A + (size_t)node * K_TOT + D_IN + lane * 8) = o.s;
}

// ---------------- K3: GEMM 128x64, BK=64, swizzled LDS, dbuf prefetch, XCD cluster ----------------

__global__ __launch_bounds__(256, 3) void gemm_kernel(const short* __restrict__ A,
                                                      const short* __restrict__ Wt,
                                                      const float* __restrict__ bias,
                                                      float* __restrict__ H) {
    __shared__ __align__(16) short smA[2][128 * BK];   // 2 x 16 KB
    __shared__ __align__(16) short smB[2][64 * BK];    // 2 x 8 KB
    const int tid = threadIdx.x;
    const int wave = tid >> 6, lane = tid & 63;

    const int s = (blockIdx.x & 7) * 79 + (blockIdx.x >> 3);   // bijective, 632=8*79
    const int m0 = (s >> 3) * 128;
    const int n0 = (s & 7) * 64;

    const int wm = wave >> 1, wn = wave & 1;
    const int rr = lane & 15, kq = lane >> 4;

    const int srow8 = lane >> 3;
    const int sslot = (lane & 7) ^ srow8;

    f32x4 acc[4][2];
#pragma unroll
    for (int i = 0; i < 4; ++i)
#pragma unroll
        for (int j = 0; j < 2; ++j) acc[i][j] = (f32x4){0.f, 0.f, 0.f, 0.f};

    int garow[4];
#pragma unroll
    for (int i = 0; i < 4; ++i) {
        int gr = m0 + (wave + 4 * i) * 8 + srow8;
        garow[i] = (gr > N_NODES - 1) ? N_NODES - 1 : gr;
    }
    int gbrow[2];
#pragma unroll
    for (int i = 0; i < 2; ++i) gbrow[i] = n0 + (wave + 4 * i) * 8 + srow8;

    auto stage = [&](int buf, int kt) {
        const int kbase = kt * BK + sslot * 8;
#pragma unroll
        for (int i = 0; i < 4; ++i)
            load_lds16(A + (size_t)garow[i] * K_TOT + kbase,
                       (char*)smA[buf] + (wave + 4 * i) * 1024);
#pragma unroll
        for (int i = 0; i < 2; ++i)
            load_lds16(Wt + (size_t)gbrow[i] * K_TOT + kbase,
                       (char*)smB[buf] + (wave + 4 * i) * 1024);
    };

    stage(0, 0);
    __syncthreads();

    for (int kt = 0; kt < K_TOT / BK; ++kt) {
        const int cur = kt & 1;
        if (kt + 1 < K_TOT / BK) stage(cur ^ 1, kt + 1);

        short8 afr[2][4], bfr[2][2];
#pragma unroll
        for (int ks = 0; ks < 2; ++ks) {
#pragma unroll
            for (int mf = 0; mf < 4; ++mf) {
                int row = wm * 64 + mf * 16 + rr;
                int slot = (ks * 4 + kq) ^ (row & 7);
                afr[ks][mf] = *(const short8*)&smA[cur][row * 64 + slot * 8];
            }
#pragma unroll
            for (int nf = 0; nf < 2; ++nf) {
                int row = wn * 32 + nf * 16 + rr;
                int slot = (ks * 4 + kq) ^ (row & 7);
                bfr[ks][nf] = *(const short8*)&smB[cur][row * 64 + slot * 8];
            }
        }
#pragma unroll
        for (int ks = 0; ks < 2; ++ks)
#pragma unroll
            for (int mf = 0; mf < 4; ++mf)
#pragma unroll
                for (int nf = 0; nf < 2; ++nf)
                    acc[mf][nf] = __builtin_amdgcn_mfma_f32_16x16x32_bf16(
                        afr[ks][mf], bfr[ks][nf], acc[mf][nf], 0, 0, 0);
        __syncthreads();
    }

#pragma unroll
    for (int mf = 0; mf < 4; ++mf) {
        int row = m0 + wm * 64 + mf * 16 + kq * 4;
#pragma unroll
        for (int nf = 0; nf < 2; ++nf) {
            int col = n0 + wn * 32 + nf * 16 + rr;
            float bv = bias[col];
#pragma unroll
            for (int r = 0; r < 4; ++r) {
                int grow = row + r;
                if (grow < N_NODES) {
                    float v = acc[mf][nf][r] + bv;
                    v = (v >= 0.f) ? v : 0.01f * v;
                    H[(size_t)grow * D_OUT + col] = v;
                }
            }
        }
    }
}

// ---------------- K4: row-wise L2 normalize (in place) ----------------

__global__ __launch_bounds__(256) void normalize_kernel(float* __restrict__ H) {
    int wave = threadIdx.x >> 6, lane = threadIdx.x & 63;
    int row = blockIdx.x * 4 + wave;
    if (row >= N_NODES) return;
    float4* p = (float4*)(H + (size_t)row * D_OUT + lane * 8);
    float4 u = p[0], v = p[1];
    float s = u.x * u.x + u.y * u.y + u.z * u.z + u.w * u.w +
              v.x * v.x + v.y * v.y + v.z * v.z + v.w * v.w;
#pragma unroll
    for (int o = 32; o > 0; o >>= 1) s += __shfl_xor(s, o);
    float scale = 1.0f / fmaxf(sqrtf(s), 1e-12f);
    u.x *= scale; u.y *= scale; u.z *= scale; u.w *= scale;
    v.x *= scale; v.y *= scale; v.z *= scale; v.w *= scale;
    p[0] = u; p[1] = v;
}

// ---------------- launch ----------------

extern "C" void kernel_launch(void* const* d_in, const int* in_sizes, int n_in,
                              void* d_out, int out_size, void* d_ws, size_t ws_size,
                              hipStream_t stream) {
    const float* x      = (const float*)d_in[0];
    const int*   src    = (const int*)d_in[1];
    const int*   dst    = (const int*)d_in[2];
    const float* Wself  = (const float*)d_in[3];
    const float* Wneigh = (const float*)d_in[4];
    const float* bias   = (const float*)d_in[5];
    float* H = (float*)d_out;

    char* ws = (char*)d_ws;
    int* deg     = (int*)ws;                          // 10000
    int* csr_src = deg + N_NODES;                     // 10000*128 ints
    size_t int_bytes = ((size_t)(N_NODES + N_NODES * SLOTS) * 4 + 255) & ~(size_t)255;
    __hip_bfloat16* Abuf = (__hip_bfloat16*)(ws + int_bytes);        // [10000][1024]
    __hip_bfloat16* Wt   = Abuf + (size_t)N_NODES * K_TOT;           // [512][1024]
    unsigned int*   x8   = (unsigned int*)(Wt + (size_t)D_OUT * K_TOT); // [10000][512] fp8

    hipMemsetAsync(deg, 0, N_NODES * sizeof(int), stream);

    k1_prep<<<625 + 512 + 2500, 256, 0, stream>>>(src, dst, deg, csr_src,
                                                  Wself, Wneigh, Wt, x, Abuf, x8);
    aggregate_kernel<<<2500, 256, 0, stream>>>(deg, csr_src, x8, Abuf);
    gemm_kernel<<<632, 256, 0, stream>>>((const short*)Abuf, (const short*)Wt, bias, H);
    normalize_kernel<<<2500, 256, 0, stream>>>(H);
}